// Round 3
// baseline (69.889 us; speedup 1.0000x reference)
//
#include <hip/hip_runtime.h>

typedef __attribute__((ext_vector_type(8))) __bf16 bf16x8;
typedef __attribute__((ext_vector_type(4))) float f32x4;

#define M_ 256
#define N_ 4096
#define K_ 4096
#define SPLITK 4
#define KC (K_ / SPLITK)   // 1024
#define BM 128
#define BN 64
#define BK 64
#define KSTEPS (KC / BK)   // 16

// ---------- helpers ----------

__device__ __forceinline__ unsigned short f2bf(float f) {
  // round-to-nearest-even fp32 -> bf16 (no NaN/inf in this data)
  unsigned int u = __builtin_bit_cast(unsigned int, f);
  u += 0x7fffu + ((u >> 16) & 1u);
  return (unsigned short)(u >> 16);
}

__device__ __forceinline__ void async16(const void* g, void* l) {
  // global -> LDS direct copy, 16B per lane; LDS dest = wave-uniform base + lane*16
  __builtin_amdgcn_global_load_lds(
      (const __attribute__((address_space(1))) unsigned int*)g,
      (__attribute__((address_space(3))) unsigned int*)l, 16, 0, 0);
}

__device__ __forceinline__ float lsq1(float y, float a, float s) {
  float yc = fminf(fmaxf(y, -a), a);
  return rintf(yc / s) * s;
}

// ---------- K1: lattice-quantize weights -> z_mod (bf16 bits) ----------
// one thread per 8-block; z[n][k] layout matches GEMM B operand [N][K].
// z dot: f32, UNFUSED mul+add, sequential ascending k — matching the XLA:CPU
// dot emitter (fmul/fadd chain, no FMA contraction). __fmul_rn/__fadd_rn
// prevent hipcc's -ffp-contract=fast from re-fusing into FMA.

__global__ __launch_bounds__(256) void k_quant(const float* __restrict__ W,
                                               const float* __restrict__ theta,
                                               const float* __restrict__ Ginv,
                                               unsigned short* __restrict__ zq,
                                               int kTheta) {
  __shared__ float Gi[64];
  const int tid = threadIdx.x;
  if (tid < 64) Gi[tid] = Ginv[tid];
  __syncthreads();
  const int bid = blockIdx.x * 256 + tid;     // 0 .. N_*K_/8-1
  const int o = bid >> 9;                     // bid / (K_/8)
  const float4* wp = (const float4*)(W + (size_t)bid * 8);
  const float4 w0 = wp[0], w1 = wp[1];
  float sc = 0.f;
  for (int t = 0; t < kTheta; ++t) sc += theta[o * kTheta + t];
  sc /= (float)kTheta;
  // W_scaled materialized in fp32 (separate rounding, matches ref)
  const float wsv[8] = {w0.x * sc, w0.y * sc, w0.z * sc, w0.w * sc,
                        w1.x * sc, w1.y * sc, w1.z * sc, w1.w * sc};
  unsigned int packed[4] = {0u, 0u, 0u, 0u};
  // bf16 bit patterns for z_mod = idx-2: idx 0->-2,1->-1,2->0,3->+1
  const unsigned long long lut = 0x3F800000BF80C000ull;
#pragma unroll
  for (int i = 0; i < 8; ++i) {
    float t = 0.f;
#pragma unroll
    for (int j = 0; j < 8; ++j)
      t = __fadd_rn(t, __fmul_rn(wsv[j], Gi[j * 8 + i]));  // unfused, sequential
    const int zi = (int)rintf(t);            // half-to-even, matches np.round
    const int idx = (zi + 2) & 3;            // ((z+2) mod 4), exact for pow2
    const unsigned int h = (unsigned int)((lut >> (idx * 16)) & 0xFFFFull);
    packed[i >> 1] |= h << ((i & 1) * 16);
  }
  *(uint4*)(zq + (size_t)bid * 8) = make_uint4(packed[0], packed[1], packed[2], packed[3]);
}

// ---------- K2: xg = x_blocks @ G^T, split into bf16 hi/lo ----------

__global__ __launch_bounds__(256) void k_xg(const float* __restrict__ x,
                                            const float* __restrict__ G,
                                            unsigned short* __restrict__ hi,
                                            unsigned short* __restrict__ lo) {
  __shared__ float Gs[64];
  const int tid = threadIdx.x;
  if (tid < 64) Gs[tid] = G[tid];
  __syncthreads();
  const int bid = blockIdx.x * 256 + tid;     // 0 .. M_*K_/8-1
  const float4* xp = (const float4*)(x + (size_t)bid * 8);
  const float4 a0 = xp[0], a1 = xp[1];
  float xv[8] = {a0.x, a0.y, a0.z, a0.w, a1.x, a1.y, a1.z, a1.w};
  unsigned int ph[4] = {0u, 0u, 0u, 0u}, pl[4] = {0u, 0u, 0u, 0u};
#pragma unroll
  for (int i = 0; i < 8; ++i) {
    float t = 0.f;
#pragma unroll
    for (int j = 0; j < 8; ++j) t = fmaf(xv[j], Gs[i * 8 + j], t);  // xg_i = sum_j x_j*G[i][j]
    const unsigned short hb = f2bf(t);
    const float hf = __builtin_bit_cast(float, (unsigned int)hb << 16);
    const unsigned short lb = f2bf(t - hf);   // exact residual, bf16-rounded
    ph[i >> 1] |= ((unsigned int)hb) << ((i & 1) * 16);
    pl[i >> 1] |= ((unsigned int)lb) << ((i & 1) * 16);
  }
  *(uint4*)(hi + (size_t)bid * 8) = make_uint4(ph[0], ph[1], ph[2], ph[3]);
  *(uint4*)(lo + (size_t)bid * 8) = make_uint4(pl[0], pl[1], pl[2], pl[3]);
}

// ---------- K3: split-K GEMM, y_part = xg_hi@z^T + xg_lo@z^T ----------
// 256 threads = 4 waves, tile 128x64, BK=64, single-buffer 2-barrier loop.
// LDS is fragment-ordered: 16x32 subtiles of 1KB, slot = lane*16 holds
// X[sub*16 + (lane&15)][kgrp(lane>>4)*8 .. +7] -> conflict-free ds_read_b128,
// staged by global_load_lds with pre-swizzled per-lane global source.

__global__ __launch_bounds__(256) void k_gemm(const unsigned short* __restrict__ xgh,
                                              const unsigned short* __restrict__ xgl,
                                              const unsigned short* __restrict__ z,
                                              float* __restrict__ part) {
  __shared__ uint4 smem4[40960 / 16];  // A_hi 16K | A_lo 16K | B 8K
  char* smem = (char*)smem4;

  const int tid = threadIdx.x;
  const int lane = tid & 63, wave = tid >> 6;
  const int b = blockIdx.x;
  const int mt = b & 1;
  const int nt = (b >> 1) & 63;
  const int sk = b >> 7;
  const int k0 = sk * KC;
  const int row_a = mt * BM, row_b = nt * BN;
  const int lrow = lane & 15, lkg = lane >> 4;

  // 40 subtile-chunks: c 0..15 = A_hi (sm = c>>1, kk = c&1), 16..31 = A_lo, 32..39 = B
  const unsigned short* src[10];
  unsigned int ldso[10];
#pragma unroll
  for (int ci = 0; ci < 10; ++ci) {
    const int c = wave * 10 + ci;
    const unsigned short* P;
    int r;
    if (c < 16) {
      P = xgh; r = row_a + (c >> 1) * 16;
    } else if (c < 32) {
      P = xgl; r = row_a + ((c - 16) >> 1) * 16;
    } else {
      P = z;   r = row_b + ((c - 32) >> 1) * 16;
    }
    const int kof = (c & 1) * 32;
    src[ci] = P + (size_t)(r + lrow) * K_ + k0 + kof + lkg * 8;
    ldso[ci] = (unsigned int)c * 1024u;
  }

  f32x4 acc[2][4] = {};

  for (int ks = 0; ks < KSTEPS; ++ks) {
#pragma unroll
    for (int ci = 0; ci < 10; ++ci)
      async16(src[ci] + (size_t)ks * BK, smem + ldso[ci]);
    __syncthreads();  // compiler drains vmcnt(0) before s_barrier

#pragma unroll
    for (int kk = 0; kk < 2; ++kk) {
      bf16x8 bfr[4], ah[2], al[2];
#pragma unroll
      for (int nf = 0; nf < 4; ++nf)
        bfr[nf] = *(const bf16x8*)(smem + (32 + nf * 2 + kk) * 1024 + lane * 16);
#pragma unroll
      for (int mf = 0; mf < 2; ++mf) {
        ah[mf] = *(const bf16x8*)(smem + ((wave * 2 + mf) * 2 + kk) * 1024 + lane * 16);
        al[mf] = *(const bf16x8*)(smem + (16 + (wave * 2 + mf) * 2 + kk) * 1024 + lane * 16);
      }
#pragma unroll
      for (int mf = 0; mf < 2; ++mf)
#pragma unroll
        for (int nf = 0; nf < 4; ++nf) {
          acc[mf][nf] = __builtin_amdgcn_mfma_f32_16x16x32_bf16(ah[mf], bfr[nf], acc[mf][nf], 0, 0, 0);
          acc[mf][nf] = __builtin_amdgcn_mfma_f32_16x16x32_bf16(al[mf], bfr[nf], acc[mf][nf], 0, 0, 0);
        }
    }
    __syncthreads();
  }

  // C/D layout (m89-verified): col = lane&15, row = (lane>>4)*4 + reg
  float* pb = part + (size_t)sk * (M_ * N_);
#pragma unroll
  for (int mf = 0; mf < 2; ++mf)
#pragma unroll
    for (int nf = 0; nf < 4; ++nf)
#pragma unroll
      for (int r = 0; r < 4; ++r) {
        const int m = row_a + wave * 32 + mf * 16 + lkg * 4 + r;
        const int n = row_b + nf * 16 + lrow;
        pb[(size_t)m * N_ + n] = acc[mf][nf][r];
      }
}

// ---------- K4: reduce split-K partials + bias + LSQ epilogue ----------

__global__ __launch_bounds__(256) void k_epi(const float* __restrict__ part,
                                             const float* __restrict__ bias,
                                             const float* __restrict__ alpha,
                                             float* __restrict__ out) {
  const int i4 = blockIdx.x * 256 + threadIdx.x;  // over M_*N_/4
  const size_t off = (size_t)i4 * 4;
  const float4 p0 = *(const float4*)(part + off);
  const float4 p1 = *(const float4*)(part + (size_t)1 * M_ * N_ + off);
  const float4 p2 = *(const float4*)(part + (size_t)2 * M_ * N_ + off);
  const float4 p3 = *(const float4*)(part + (size_t)3 * M_ * N_ + off);
  const int n = (int)(off & (N_ - 1));
  const float4 bv = *(const float4*)(bias + n);
  const float a = fmaxf(alpha[0], 0.f) + 1e-8f;  // relu(alpha)+1e-8
  const float s = a / 127.0f;
  float4 o;
  o.x = lsq1(((p0.x + p1.x) + p2.x) + p3.x + bv.x, a, s);
  o.y = lsq1(((p0.y + p1.y) + p2.y) + p3.y + bv.y, a, s);
  o.z = lsq1(((p0.z + p1.z) + p2.z) + p3.z + bv.z, a, s);
  o.w = lsq1(((p0.w + p1.w) + p2.w) + p3.w + bv.w, a, s);
  *(float4*)(out + off) = o;
}

// ---------- launch ----------

extern "C" void kernel_launch(void* const* d_in, const int* in_sizes, int n_in,
                              void* d_out, int out_size, void* d_ws, size_t ws_size,
                              hipStream_t stream) {
  const float* x     = (const float*)d_in[0];
  const float* W     = (const float*)d_in[1];
  const float* bias  = (const float*)d_in[2];
  const float* theta = (const float*)d_in[3];
  const float* alpha = (const float*)d_in[4];
  const float* G     = (const float*)d_in[5];
  const float* Ginv  = (const float*)d_in[6];
  float* out = (float*)d_out;

  const int O = in_sizes[2];           // 4096
  const int kTheta = in_sizes[3] / O;  // 1

  // ws layout: z bf16 [N][K] 32MB | xg_hi 2MB | xg_lo 2MB | partials [S][M][N] 16MB
  char* ws = (char*)d_ws;
  unsigned short* zq  = (unsigned short*)ws;
  unsigned short* xgh = (unsigned short*)(ws + 33554432);
  unsigned short* xgl = (unsigned short*)(ws + 35651584);
  float* part = (float*)(ws + 37748736);
  if (ws_size < 54525952) return;  // guard: need 52MB scratch

  k_quant<<<(N_ * K_ / 8) / 256, 256, 0, stream>>>(W, theta, Ginv, zq, kTheta);
  k_xg<<<(M_ * K_ / 8) / 256, 256, 0, stream>>>(x, G, xgh, xgl);
  k_gemm<<<2 * 64 * SPLITK, 256, 0, stream>>>(xgh, xgl, zq, part);
  k_epi<<<(M_ * N_ / 4) / 256, 256, 0, stream>>>(part, bias, alpha, out);
}